// Round 18
// baseline (3286.694 us; speedup 1.0000x reference)
//
#include <hip/hip_runtime.h>
#include <hip/hip_bf16.h>
#include <cstdint>
#include <cstddef>

typedef __bf16 bf16_t;
typedef bf16_t bf16x8 __attribute__((ext_vector_type(8)));
typedef bf16_t bf16x4 __attribute__((ext_vector_type(4)));
typedef float  f32x4  __attribute__((ext_vector_type(4)));
typedef int    i32x4  __attribute__((ext_vector_type(4)));

#define TOK 16384   // B*S
#define Hh  1024    // hidden
#define F2  2048    // 2*H
#define NC  4096    // interleaved expert cols: h*4+d

__device__ __forceinline__ void gload_lds16(const bf16_t* g, bf16_t* lds) {
  __builtin_amdgcn_global_load_lds(
      (const __attribute__((address_space(1))) void*)g,
      (__attribute__((address_space(3))) void*)lds, 16, 0, 0);
}
__device__ __forceinline__ void gload_lds16b(const int8_t* g, int8_t* lds) {
  __builtin_amdgcn_global_load_lds(
      (const __attribute__((address_space(1))) void*)g,
      (__attribute__((address_space(3))) void*)lds, 16, 0, 0);
}

// ---- Wf [1024][2048] fp32 -> wft [2048][1024] bf16 (tiled transpose) ----
__global__ __launch_bounds__(256)
void k_tr_wf(const float* __restrict__ in, bf16_t* __restrict__ out) {
  __shared__ float T[64][65];
  const int f0 = blockIdx.x * 64, h0 = blockIdx.y * 64;
  const int tid = threadIdx.x;
  const int c4 = (tid & 15) * 4, r = tid >> 4;
  #pragma unroll
  for (int p = 0; p < 4; ++p) {
    int hh = p * 16 + r;
    float4 v = *(const float4*)&in[(size_t)(h0 + hh) * F2 + f0 + c4];
    T[c4 + 0][hh] = v.x; T[c4 + 1][hh] = v.y; T[c4 + 2][hh] = v.z; T[c4 + 3][hh] = v.w;
  }
  __syncthreads();
  #pragma unroll
  for (int p = 0; p < 4; ++p) {
    int ff = p * 16 + r;
    bf16x4 o = { (bf16_t)T[ff][c4 + 0], (bf16_t)T[ff][c4 + 1],
                 (bf16_t)T[ff][c4 + 2], (bf16_t)T[ff][c4 + 3] };
    *(bf16x4*)&out[(size_t)(f0 + ff) * Hh + h0 + c4] = o;
  }
}

// ---- pass 1: per (cp, f-chunk) maxabs of We ----
__global__ void k_we_scale1(const float* __restrict__ We, float* __restrict__ pmax) {
  int ht = blockIdx.x, fc = blockIdx.y, d = blockIdx.z;
  int h = ht * 256 + threadIdx.x;
  float m = 0.f;
  for (int ff = 0; ff < 256; ++ff) {
    float v = We[((size_t)d * F2 + fc * 256 + ff) * Hh + h];
    m = fmaxf(m, fabsf(v));
  }
  pmax[(size_t)(h * 4 + d) * 8 + fc] = m;
}
// ---- pass 2: reduce -> SB[cp] ----
__global__ void k_we_scale2(const float* __restrict__ pmax, float* __restrict__ SB) {
  int cp = blockIdx.x * 256 + threadIdx.x;
  float m = 0.f;
  #pragma unroll
  for (int i = 0; i < 8; ++i) m = fmaxf(m, pmax[(size_t)cp * 8 + i]);
  SB[cp] = m;
}

// ---- We -> wet_i8 [4096][2048], row cp = h*4+d, quantized ----
__global__ __launch_bounds__(256)
void k_tr_we(const float* __restrict__ in, const float* __restrict__ SB,
             int8_t* __restrict__ out) {
  __shared__ float T[64][65];
  const int f0 = blockIdx.x * 64, h0 = blockIdx.y * 64, d = blockIdx.z;
  const float* ind = in + (size_t)d * F2 * Hh;
  const int tid = threadIdx.x;
  const int c4 = (tid & 15) * 4, r = tid >> 4;
  #pragma unroll
  for (int p = 0; p < 4; ++p) {
    int ff = p * 16 + r;
    float4 v = *(const float4*)&ind[(size_t)(f0 + ff) * Hh + h0 + c4];
    T[c4 + 0][ff] = v.x; T[c4 + 1][ff] = v.y; T[c4 + 2][ff] = v.z; T[c4 + 3][ff] = v.w;
  }
  __syncthreads();
  #pragma unroll
  for (int p = 0; p < 4; ++p) {
    int hh = p * 16 + r;
    int cp = (h0 + hh) * 4 + d;
    float m = SB[cp];
    float inv = (m > 1e-30f) ? 127.f / m : 0.f;
    char4 o;
    o.x = (int8_t)__float2int_rn(T[hh][c4 + 0] * inv);
    o.y = (int8_t)__float2int_rn(T[hh][c4 + 1] * inv);
    o.z = (int8_t)__float2int_rn(T[hh][c4 + 2] * inv);
    o.w = (int8_t)__float2int_rn(T[hh][c4 + 3] * inv);
    *(char4*)&out[(size_t)cp * F2 + f0 + c4] = o;
  }
}

// ---- fused: router logits + x fp32->bf16 convert (wave per token) ----
__global__ void k_router_w(const float* __restrict__ x, const float* __restrict__ vol,
                           const float* __restrict__ risk, const float* __restrict__ clsb,
                           const float* __restrict__ vw, const float* __restrict__ vb,
                           const float* __restrict__ rw, const float* __restrict__ rb,
                           const float* __restrict__ sw, const float* __restrict__ sb,
                           bf16_t* __restrict__ xbf, float* __restrict__ LP,
                           int m0, int Tc) {
  int w = threadIdx.x >> 6, l = threadIdx.x & 63;
  int t = blockIdx.x * 4 + w;
  if (t >= Tc) return;
  int s = m0 + t;
  const float4* xr = (const float4*)(x + (size_t)s * Hh);
  bf16x4* xo = (bf16x4*)(xbf + (size_t)s * Hh);
  float sum = 0.f, sq = 0.f, mx = -1e30f;
  #pragma unroll
  for (int it = 0; it < 4; ++it) {
    float4 v = xr[it * 64 + l];
    sum += v.x + v.y + v.z + v.w;
    sq  += v.x * v.x + v.y * v.y + v.z * v.z + v.w * v.w;
    mx = fmaxf(mx, fmaxf(fmaxf(v.x, v.y), fmaxf(v.z, v.w)));
    bf16x4 o = { (bf16_t)v.x, (bf16_t)v.y, (bf16_t)v.z, (bf16_t)v.w };
    xo[it * 64 + l] = o;
  }
  #pragma unroll
  for (int off = 32; off; off >>= 1) {
    sum += __shfl_xor(sum, off, 64);
    sq  += __shfl_xor(sq,  off, 64);
    mx   = fmaxf(mx, __shfl_xor(mx, off, 64));
  }
  if (l < 4) {
    int d = l;
    float mean = sum * (1.0f / Hh);
    float var  = sq * (1.0f / Hh) - mean * mean;
    float sd   = sqrtf(fmaxf(var, 0.f));
    float v = vol[s], rk = risk[s];
    float acc = clsb[d];
    #pragma unroll
    for (int k = 0; k < 8; ++k)  acc += tanhf(v  * vw[k*4+d] + vb[k*4+d]);
    #pragma unroll
    for (int k = 0; k < 8; ++k)  acc += tanhf(rk * rw[k*4+d] + rb[k*4+d]);
    #pragma unroll
    for (int k = 0; k < 12; ++k)
      acc += tanhf(mean * sw[k*4+d] + sd * sw[48 + k*4+d] + mx * sw[96 + k*4+d] + sb[k*4+d]);
    LP[t * 4 + d] = acc;
  }
}

// ---- dom logits + softmax (wave per token), i8 feat input ----
__global__ void k_dom(const int8_t* __restrict__ feat, const float* __restrict__ Wc,
                      float* __restrict__ LP) {
  int w = threadIdx.x >> 6, l = threadIdx.x & 63;
  int t = blockIdx.x * 4 + w;
  const int8_t* fr = feat + (size_t)t * F2;
  const float4* Wc4 = (const float4*)Wc;
  float a0 = 0, a1 = 0, a2 = 0, a3 = 0;
  #pragma unroll
  for (int it = 0; it < 4; ++it) {
    int f0 = it * 512 + l * 8;
    int2 v = *(const int2*)(fr + f0);
    #pragma unroll
    for (int j = 0; j < 8; ++j) {
      int word = (j < 4) ? v.x : v.y;
      float vf = (float)((signed char)(word >> (8 * (j & 3)))) * (1.f / 127.f);
      float4 wv = Wc4[f0 + j];
      a0 += vf * wv.x; a1 += vf * wv.y; a2 += vf * wv.z; a3 += vf * wv.w;
    }
  }
  #pragma unroll
  for (int off = 32; off; off >>= 1) {
    a0 += __shfl_xor(a0, off, 64); a1 += __shfl_xor(a1, off, 64);
    a2 += __shfl_xor(a2, off, 64); a3 += __shfl_xor(a3, off, 64);
  }
  if (l == 0) {
    float l0 = a0 + LP[t*4+0], l1 = a1 + LP[t*4+1];
    float l2 = a2 + LP[t*4+2], l3 = a3 + LP[t*4+3];
    float m = fmaxf(fmaxf(l0, l1), fmaxf(l2, l3));
    float e0 = expf(l0 - m), e1 = expf(l1 - m), e2 = expf(l2 - m), e3 = expf(l3 - m);
    float inv = 1.f / (e0 + e1 + e2 + e3);
    LP[t*4+0] = e0 * inv; LP[t*4+1] = e1 * inv; LP[t*4+2] = e2 * inv; LP[t*4+3] = e3 * inv;
  }
}

// ---------------- GEMM 1: 256x256 block, 16 waves (4x4), wave 64x64, 2-buf LDS ----------------
__global__ __launch_bounds__(1024, 8)
void k_feat_gemm256(const bf16_t* __restrict__ A, const bf16_t* __restrict__ Bt,
                    const float* __restrict__ bias, int8_t* __restrict__ feat, int nbm) {
  constexpr int K = Hh, NT = K / 32;          // 32 tiles of K=32
  __shared__ bf16_t lds[2 * 8192 * 2];        // A: 2 bufs x [256][32]; B: 2 x [256][32]
  bf16_t* ldsB = lds + 16384;
  const int tid = threadIdx.x;
  const int l = tid & 63, wid = tid >> 6;
  const int wm = wid >> 2, wn = wid & 3;      // 4 x 4 waves, wave tile 64x64
  const int l15 = l & 15, lg = l >> 4;

  const int nwg = nbm * 8, cpx = nwg >> 3;    // F2/256 = 8 bn panels
  int swzb = (blockIdx.x & 7) * cpx + (blockIdx.x >> 3);
  const int bm = swzb % nbm, bn = swzb / nbm;

  const bf16_t* gA = A  + (size_t)(bm * 256) * K;
  const bf16_t* gB = Bt + (size_t)(bn * 256) * K;

  // staging: 1024 granules per 16KB tile -> one gload per thread per operand
  const int sRow = tid >> 2;
  const int sGx  = ((tid & 3) ^ ((sRow >> 1) & 3)) << 3;   // elements

  #define STAGE(ts) do {                                                       \
    int b_ = (ts) & 1;                                                         \
    gload_lds16(gA + (size_t)sRow * K + (ts) * 32 + sGx, lds  + b_ * 8192 + tid * 8); \
    gload_lds16(gB + (size_t)sRow * K + (ts) * 32 + sGx, ldsB + b_ * 8192 + tid * 8); \
  } while (0)
  #define FENCE asm volatile("" ::: "memory")

  const int cswz = ((lg ^ ((l15 >> 1) & 3)) << 3);
  f32x4 acc[4][4] = {};

  STAGE(0);
  asm volatile("s_waitcnt vmcnt(0)" ::: "memory");
  FENCE; __builtin_amdgcn_s_barrier(); FENCE;

  for (int t = 0; t < NT; ++t) {
    const bf16_t* As_ = lds  + (t & 1) * 8192;
    const bf16_t* Bs_ = ldsB + (t & 1) * 8192;
    if (t + 1 < NT) STAGE(t + 1);
    bf16x8 af[4], bf[4];
    #pragma unroll
    for (int ni = 0; ni < 4; ++ni)
      bf[ni] = *(const bf16x8*)&Bs_[(wn * 64 + ni * 16 + l15) * 32 + cswz];
    #pragma unroll
    for (int mi = 0; mi < 4; ++mi)
      af[mi] = *(const bf16x8*)&As_[(wm * 64 + mi * 16 + l15) * 32 + cswz];
    __builtin_amdgcn_s_setprio(1);
    #pragma unroll
    for (int ni = 0; ni < 4; ++ni)
      #pragma unroll
      for (int mi = 0; mi < 4; ++mi)
        acc[mi][ni] = __builtin_amdgcn_mfma_f32_16x16x32_bf16(af[mi], bf[ni], acc[mi][ni], 0, 0, 0);
    __builtin_amdgcn_s_setprio(0);
    asm volatile("s_waitcnt vmcnt(0)" ::: "memory");
    FENCE; __builtin_amdgcn_s_barrier(); FENCE;
  }
  #undef STAGE
  #undef FENCE

  // epilogue: feat_i8 = round(tanh(acc + bias) * 127)
  #pragma unroll
  for (int ni = 0; ni < 4; ++ni) {
    int gn = bn * 256 + wn * 64 + ni * 16 + l15;
    float bv = bias[gn];
    #pragma unroll
    for (int mi = 0; mi < 4; ++mi) {
      int gmBase = bm * 256 + wm * 64 + mi * 16 + lg * 4;
      #pragma unroll
      for (int r = 0; r < 4; ++r) {
        float tv = tanhf(acc[mi][ni][r] + bv);
        feat[(size_t)(gmBase + r) * F2 + gn] = (int8_t)__float2int_rn(tv * 127.f);
      }
    }
  }
}

// ---------------- GEMM 2: 256x256 block, 16 waves (4x4), wave 64x64, 2-buf LDS, i8 ----------------
__global__ __launch_bounds__(1024, 8)
void k_expert_gemm256(const int8_t* __restrict__ A, const int8_t* __restrict__ Bt,
                      const float* __restrict__ P, const float* __restrict__ EB,
                      const float* __restrict__ SBq, float* __restrict__ out, int nbm) {
  constexpr int K = F2, NT = K / 64;          // 32 tiles of K=64
  __shared__ int8_t lds[2 * 16384 * 2];       // A: 2 x [256][64]B; B: 2 x [256][64]B
  int8_t* ldsB = lds + 32768;
  const int tid = threadIdx.x;
  const int l = tid & 63, wid = tid >> 6;
  const int wm = wid >> 2, wn = wid & 3;      // 4 x 4 waves, wave tile 64x64
  const int l15 = l & 15, lg = l >> 4;

  const int nwg = nbm * 16, cpx = nwg >> 3;   // NC/256 = 16 bn panels
  int swzb = (blockIdx.x & 7) * cpx + (blockIdx.x >> 3);
  const int bm = swzb % nbm, bn = swzb / nbm;

  const int8_t* gA = A  + (size_t)(bm * 256) * K;
  const int8_t* gB = Bt + (size_t)(bn * 256) * K;

  const int sRow = tid >> 2;
  const int sGx  = ((tid & 3) ^ ((sRow >> 1) & 3)) << 4;   // bytes

  #define STAGE(ts) do {                                                       \
    int b_ = (ts) & 1;                                                         \
    gload_lds16b(gA + (size_t)sRow * K + (ts) * 64 + sGx, lds  + b_ * 16384 + tid * 16); \
    gload_lds16b(gB + (size_t)sRow * K + (ts) * 64 + sGx, ldsB + b_ * 16384 + tid * 16); \
  } while (0)
  #define FENCE asm volatile("" ::: "memory")

  const int cswzB = ((lg ^ ((l15 >> 1) & 3)) << 4);
  i32x4 acc[4][4] = {};

  STAGE(0);
  asm volatile("s_waitcnt vmcnt(0)" ::: "memory");
  FENCE; __builtin_amdgcn_s_barrier(); FENCE;

  for (int t = 0; t < NT; ++t) {
    const int8_t* As_ = lds  + (t & 1) * 16384;
    const int8_t* Bs_ = ldsB + (t & 1) * 16384;
    if (t + 1 < NT) STAGE(t + 1);
    i32x4 af[4], bf[4];
    #pragma unroll
    for (int ni = 0; ni < 4; ++ni)
      bf[ni] = *(const i32x4*)&Bs_[(wn * 64 + ni * 16 + l15) * 64 + cswzB];
    #pragma unroll
    for (int mi = 0; mi < 4; ++mi)
      af[mi] = *(const i32x4*)&As_[(wm * 64 + mi * 16 + l15) * 64 + cswzB];
    __builtin_amdgcn_s_setprio(1);
    #pragma unroll
    for (int ni = 0; ni < 4; ++ni)
      #pragma unroll
      for (int mi = 0; mi < 4; ++mi)
        acc[mi][ni] = __builtin_amdgcn_mfma_i32_16x16x64_i8(af[mi], bf[ni], acc[mi][ni], 0, 0, 0);
    __builtin_amdgcn_s_setprio(0);
    asm volatile("s_waitcnt vmcnt(0)" ::: "memory");
    FENCE; __builtin_amdgcn_s_barrier(); FENCE;
  }
  #undef STAGE
  #undef FENCE

  // epilogue: dequant + gated combine -> fp32 out
  #pragma unroll
  for (int mi = 0; mi < 4; ++mi) {
    int gmBase = bm * 256 + wm * 64 + mi * 16 + lg * 4;
    float pr[4];
    #pragma unroll
    for (int r = 0; r < 4; ++r) pr[r] = P[(gmBase + r) * 4 + (l & 3)];
    #pragma unroll
    for (int ni = 0; ni < 4; ++ni) {
      int colp = bn * 256 + wn * 64 + ni * 16 + l15;
      int h = colp >> 2;
      float dq = SBq[colp] * (1.0f / 16129.0f);
      #pragma unroll
      for (int r = 0; r < 4; ++r) {
        float sv = (float)acc[mi][ni][r] * dq * pr[r];
        sv += __shfl_xor(sv, 1, 64);
        sv += __shfl_xor(sv, 2, 64);
        if ((l & 3) == 0) {
          int gm = gmBase + r;
          float bt = P[gm*4+0]*EB[h] + P[gm*4+1]*EB[Hh+h]
                   + P[gm*4+2]*EB[2*Hh+h] + P[gm*4+3]*EB[3*Hh+h];
          out[(size_t)gm * Hh + h] = sv + bt;
        }
      }
    }
  }
}

extern "C" void kernel_launch(void* const* d_in, const int* in_sizes, int n_in,
                              void* d_out, int out_size, void* d_ws, size_t ws_size,
                              hipStream_t stream) {
  const float *x  = (const float*)d_in[0],  *vol = (const float*)d_in[1];
  const float *risk = (const float*)d_in[2], *Wf = (const float*)d_in[3];
  const float *fb = (const float*)d_in[4],  *Wc = (const float*)d_in[5];
  const float *cb = (const float*)d_in[6],  *vw = (const float*)d_in[7];
  const float *vb = (const float*)d_in[8],  *rw = (const float*)d_in[9];
  const float *rb = (const float*)d_in[10], *sw = (const float*)d_in[11];
  const float *sb = (const float*)d_in[12], *We = (const float*)d_in[13];
  const float *eb = (const float*)d_in[14];

  float* out = (float*)d_out;   // fp32 output
  char* ws = (char*)d_ws;
  const size_t KB = 1024, MB = 1024 * 1024;

  float*  LP     = (float*) ws;                        // 256 KB
  float*  SBq    = (float*) (ws + 256 * KB);           // 16 KB
  float*  pmax   = (float*) (ws + 512 * KB);           // 128 KB
  bf16_t* wft    = (bf16_t*)(ws + 1 * MB);             // 4 MB
  int8_t* wet    = (int8_t*)(ws + 5 * MB);             // 8 MB
  bf16_t* xbf    = (bf16_t*)(ws + 13 * MB);            // 32 MB
  const size_t base = 45 * MB;
  int Tc = TOK;
  while (Tc > 1024 && base + (size_t)Tc * F2 > ws_size) Tc >>= 1;
  int8_t* feat = (int8_t*)(ws + base);                 // Tc * 2 KB

  k_tr_wf    <<<dim3(F2 / 64, Hh / 64), 256, 0, stream>>>(Wf, wft);
  k_we_scale1<<<dim3(4, 8, 4), 256, 0, stream>>>(We, pmax);
  k_we_scale2<<<16, 256, 0, stream>>>(pmax, SBq);
  k_tr_we    <<<dim3(F2 / 64, Hh / 64, 4), 256, 0, stream>>>(We, SBq, wet);

  for (int m0 = 0; m0 < TOK; m0 += Tc) {
    k_router_w<<<Tc / 4, 256, 0, stream>>>(
        x, vol, risk, cb, vw, vb, rw, rb, sw, sb, xbf, LP, m0, Tc);
    int nbmF = Tc / 256;
    k_feat_gemm256<<<nbmF * (F2 / 256), 1024, 0, stream>>>(
        xbf + (size_t)m0 * Hh, wft, fb, feat, nbmF);
    k_dom<<<Tc / 4, 256, 0, stream>>>(feat, Wc, LP);
    k_expert_gemm256<<<nbmF * (NC / 256), 1024, 0, stream>>>(
        feat, wet, LP, eb, SBq, out + (size_t)m0 * Hh, nbmF);
  }
}

// Round 19
// 447.206 us; speedup vs baseline: 7.3494x; 7.3494x over previous
//
#include <hip/hip_runtime.h>
#include <hip/hip_bf16.h>
#include <cstdint>
#include <cstddef>

typedef __bf16 bf16_t;
typedef bf16_t bf16x8 __attribute__((ext_vector_type(8)));
typedef bf16_t bf16x4 __attribute__((ext_vector_type(4)));
typedef float  f32x4  __attribute__((ext_vector_type(4)));
typedef int    i32x4  __attribute__((ext_vector_type(4)));

#define TOK 16384   // B*S
#define Hh  1024    // hidden
#define F2  2048    // 2*H
#define NC  4096    // interleaved expert cols: h*4+d

__device__ __forceinline__ void gload_lds16(const bf16_t* g, bf16_t* lds) {
  __builtin_amdgcn_global_load_lds(
      (const __attribute__((address_space(1))) void*)g,
      (__attribute__((address_space(3))) void*)lds, 16, 0, 0);
}
__device__ __forceinline__ void gload_lds16b(const int8_t* g, int8_t* lds) {
  __builtin_amdgcn_global_load_lds(
      (const __attribute__((address_space(1))) void*)g,
      (__attribute__((address_space(3))) void*)lds, 16, 0, 0);
}

// ---- Wf [1024][2048] fp32 -> wft [2048][1024] bf16 (tiled transpose) ----
__global__ __launch_bounds__(256)
void k_tr_wf(const float* __restrict__ in, bf16_t* __restrict__ out) {
  __shared__ float T[64][65];
  const int f0 = blockIdx.x * 64, h0 = blockIdx.y * 64;
  const int tid = threadIdx.x;
  const int c4 = (tid & 15) * 4, r = tid >> 4;
  #pragma unroll
  for (int p = 0; p < 4; ++p) {
    int hh = p * 16 + r;
    float4 v = *(const float4*)&in[(size_t)(h0 + hh) * F2 + f0 + c4];
    T[c4 + 0][hh] = v.x; T[c4 + 1][hh] = v.y; T[c4 + 2][hh] = v.z; T[c4 + 3][hh] = v.w;
  }
  __syncthreads();
  #pragma unroll
  for (int p = 0; p < 4; ++p) {
    int ff = p * 16 + r;
    bf16x4 o = { (bf16_t)T[ff][c4 + 0], (bf16_t)T[ff][c4 + 1],
                 (bf16_t)T[ff][c4 + 2], (bf16_t)T[ff][c4 + 3] };
    *(bf16x4*)&out[(size_t)(f0 + ff) * Hh + h0 + c4] = o;
  }
}

// ---- pass 1: per (cp, f-chunk) maxabs of We ----
__global__ void k_we_scale1(const float* __restrict__ We, float* __restrict__ pmax) {
  int ht = blockIdx.x, fc = blockIdx.y, d = blockIdx.z;
  int h = ht * 256 + threadIdx.x;
  float m = 0.f;
  for (int ff = 0; ff < 256; ++ff) {
    float v = We[((size_t)d * F2 + fc * 256 + ff) * Hh + h];
    m = fmaxf(m, fabsf(v));
  }
  pmax[(size_t)(h * 4 + d) * 8 + fc] = m;
}
// ---- pass 2: reduce -> SB[cp] ----
__global__ void k_we_scale2(const float* __restrict__ pmax, float* __restrict__ SB) {
  int cp = blockIdx.x * 256 + threadIdx.x;
  float m = 0.f;
  #pragma unroll
  for (int i = 0; i < 8; ++i) m = fmaxf(m, pmax[(size_t)cp * 8 + i]);
  SB[cp] = m;
}

// ---- We -> wet_i8 [4096][2048], row cp = h*4+d, quantized ----
__global__ __launch_bounds__(256)
void k_tr_we(const float* __restrict__ in, const float* __restrict__ SB,
             int8_t* __restrict__ out) {
  __shared__ float T[64][65];
  const int f0 = blockIdx.x * 64, h0 = blockIdx.y * 64, d = blockIdx.z;
  const float* ind = in + (size_t)d * F2 * Hh;
  const int tid = threadIdx.x;
  const int c4 = (tid & 15) * 4, r = tid >> 4;
  #pragma unroll
  for (int p = 0; p < 4; ++p) {
    int ff = p * 16 + r;
    float4 v = *(const float4*)&ind[(size_t)(f0 + ff) * Hh + h0 + c4];
    T[c4 + 0][ff] = v.x; T[c4 + 1][ff] = v.y; T[c4 + 2][ff] = v.z; T[c4 + 3][ff] = v.w;
  }
  __syncthreads();
  #pragma unroll
  for (int p = 0; p < 4; ++p) {
    int hh = p * 16 + r;
    int cp = (h0 + hh) * 4 + d;
    float m = SB[cp];
    float inv = (m > 1e-30f) ? 127.f / m : 0.f;
    char4 o;
    o.x = (int8_t)__float2int_rn(T[hh][c4 + 0] * inv);
    o.y = (int8_t)__float2int_rn(T[hh][c4 + 1] * inv);
    o.z = (int8_t)__float2int_rn(T[hh][c4 + 2] * inv);
    o.w = (int8_t)__float2int_rn(T[hh][c4 + 3] * inv);
    *(char4*)&out[(size_t)cp * F2 + f0 + c4] = o;
  }
}

// ---- fused: router logits + x fp32->bf16 convert (wave per token) ----
__global__ void k_router_w(const float* __restrict__ x, const float* __restrict__ vol,
                           const float* __restrict__ risk, const float* __restrict__ clsb,
                           const float* __restrict__ vw, const float* __restrict__ vb,
                           const float* __restrict__ rw, const float* __restrict__ rb,
                           const float* __restrict__ sw, const float* __restrict__ sb,
                           bf16_t* __restrict__ xbf, float* __restrict__ LP,
                           int m0, int Tc) {
  int w = threadIdx.x >> 6, l = threadIdx.x & 63;
  int t = blockIdx.x * 4 + w;
  if (t >= Tc) return;
  int s = m0 + t;
  const float4* xr = (const float4*)(x + (size_t)s * Hh);
  bf16x4* xo = (bf16x4*)(xbf + (size_t)s * Hh);
  float sum = 0.f, sq = 0.f, mx = -1e30f;
  #pragma unroll
  for (int it = 0; it < 4; ++it) {
    float4 v = xr[it * 64 + l];
    sum += v.x + v.y + v.z + v.w;
    sq  += v.x * v.x + v.y * v.y + v.z * v.z + v.w * v.w;
    mx = fmaxf(mx, fmaxf(fmaxf(v.x, v.y), fmaxf(v.z, v.w)));
    bf16x4 o = { (bf16_t)v.x, (bf16_t)v.y, (bf16_t)v.z, (bf16_t)v.w };
    xo[it * 64 + l] = o;
  }
  #pragma unroll
  for (int off = 32; off; off >>= 1) {
    sum += __shfl_xor(sum, off, 64);
    sq  += __shfl_xor(sq,  off, 64);
    mx   = fmaxf(mx, __shfl_xor(mx, off, 64));
  }
  if (l < 4) {
    int d = l;
    float mean = sum * (1.0f / Hh);
    float var  = sq * (1.0f / Hh) - mean * mean;
    float sd   = sqrtf(fmaxf(var, 0.f));
    float v = vol[s], rk = risk[s];
    float acc = clsb[d];
    #pragma unroll
    for (int k = 0; k < 8; ++k)  acc += tanhf(v  * vw[k*4+d] + vb[k*4+d]);
    #pragma unroll
    for (int k = 0; k < 8; ++k)  acc += tanhf(rk * rw[k*4+d] + rb[k*4+d]);
    #pragma unroll
    for (int k = 0; k < 12; ++k)
      acc += tanhf(mean * sw[k*4+d] + sd * sw[48 + k*4+d] + mx * sw[96 + k*4+d] + sb[k*4+d]);
    LP[t * 4 + d] = acc;
  }
}

// ---- dom logits + softmax (wave per token), i8 feat input ----
__global__ void k_dom(const int8_t* __restrict__ feat, const float* __restrict__ Wc,
                      float* __restrict__ LP) {
  int w = threadIdx.x >> 6, l = threadIdx.x & 63;
  int t = blockIdx.x * 4 + w;
  const int8_t* fr = feat + (size_t)t * F2;
  const float4* Wc4 = (const float4*)Wc;
  float a0 = 0, a1 = 0, a2 = 0, a3 = 0;
  #pragma unroll
  for (int it = 0; it < 4; ++it) {
    int f0 = it * 512 + l * 8;
    int2 v = *(const int2*)(fr + f0);
    #pragma unroll
    for (int j = 0; j < 8; ++j) {
      int word = (j < 4) ? v.x : v.y;
      float vf = (float)((signed char)(word >> (8 * (j & 3)))) * (1.f / 127.f);
      float4 wv = Wc4[f0 + j];
      a0 += vf * wv.x; a1 += vf * wv.y; a2 += vf * wv.z; a3 += vf * wv.w;
    }
  }
  #pragma unroll
  for (int off = 32; off; off >>= 1) {
    a0 += __shfl_xor(a0, off, 64); a1 += __shfl_xor(a1, off, 64);
    a2 += __shfl_xor(a2, off, 64); a3 += __shfl_xor(a3, off, 64);
  }
  if (l == 0) {
    float l0 = a0 + LP[t*4+0], l1 = a1 + LP[t*4+1];
    float l2 = a2 + LP[t*4+2], l3 = a3 + LP[t*4+3];
    float m = fmaxf(fmaxf(l0, l1), fmaxf(l2, l3));
    float e0 = expf(l0 - m), e1 = expf(l1 - m), e2 = expf(l2 - m), e3 = expf(l3 - m);
    float inv = 1.f / (e0 + e1 + e2 + e3);
    LP[t*4+0] = e0 * inv; LP[t*4+1] = e1 * inv; LP[t*4+2] = e2 * inv; LP[t*4+3] = e3 * inv;
  }
}

// ---------------- GEMM 1: 256x256 block, 16 waves (4x4), wave 64x64, 2-buf LDS ----------------
__global__ __launch_bounds__(1024, 4)
void k_feat_gemm256(const bf16_t* __restrict__ A, const bf16_t* __restrict__ Bt,
                    const float* __restrict__ bias, int8_t* __restrict__ feat, int nbm) {
  constexpr int K = Hh, NT = K / 32;          // 32 tiles of K=32
  __shared__ bf16_t lds[2 * 8192 * 2];        // A: 2 bufs x [256][32]; B: 2 x [256][32]
  bf16_t* ldsB = lds + 16384;
  const int tid = threadIdx.x;
  const int l = tid & 63, wid = tid >> 6;
  const int wm = wid >> 2, wn = wid & 3;      // 4 x 4 waves, wave tile 64x64
  const int l15 = l & 15, lg = l >> 4;

  const int nwg = nbm * 8, cpx = nwg >> 3;    // F2/256 = 8 bn panels
  int swzb = (blockIdx.x & 7) * cpx + (blockIdx.x >> 3);
  const int bm = swzb % nbm, bn = swzb / nbm;

  const bf16_t* gA = A  + (size_t)(bm * 256) * K;
  const bf16_t* gB = Bt + (size_t)(bn * 256) * K;

  // staging: 1024 granules per 16KB tile -> one gload per thread per operand
  const int sRow = tid >> 2;
  const int sGx  = ((tid & 3) ^ ((sRow >> 1) & 3)) << 3;   // elements

  #define STAGE(ts) do {                                                       \
    int b_ = (ts) & 1;                                                         \
    gload_lds16(gA + (size_t)sRow * K + (ts) * 32 + sGx, lds  + b_ * 8192 + tid * 8); \
    gload_lds16(gB + (size_t)sRow * K + (ts) * 32 + sGx, ldsB + b_ * 8192 + tid * 8); \
  } while (0)
  #define FENCE asm volatile("" ::: "memory")

  const int cswz = ((lg ^ ((l15 >> 1) & 3)) << 3);
  f32x4 acc[4][4] = {};

  STAGE(0);
  asm volatile("s_waitcnt vmcnt(0)" ::: "memory");
  FENCE; __builtin_amdgcn_s_barrier(); FENCE;

  for (int t = 0; t < NT; ++t) {
    const bf16_t* As_ = lds  + (t & 1) * 8192;
    const bf16_t* Bs_ = ldsB + (t & 1) * 8192;
    if (t + 1 < NT) STAGE(t + 1);
    bf16x8 af[4], bf[4];
    #pragma unroll
    for (int ni = 0; ni < 4; ++ni)
      bf[ni] = *(const bf16x8*)&Bs_[(wn * 64 + ni * 16 + l15) * 32 + cswz];
    #pragma unroll
    for (int mi = 0; mi < 4; ++mi)
      af[mi] = *(const bf16x8*)&As_[(wm * 64 + mi * 16 + l15) * 32 + cswz];
    __builtin_amdgcn_s_setprio(1);
    #pragma unroll
    for (int ni = 0; ni < 4; ++ni)
      #pragma unroll
      for (int mi = 0; mi < 4; ++mi)
        acc[mi][ni] = __builtin_amdgcn_mfma_f32_16x16x32_bf16(af[mi], bf[ni], acc[mi][ni], 0, 0, 0);
    __builtin_amdgcn_s_setprio(0);
    asm volatile("s_waitcnt vmcnt(0)" ::: "memory");
    FENCE; __builtin_amdgcn_s_barrier(); FENCE;
  }
  #undef STAGE
  #undef FENCE

  // epilogue: feat_i8 = round(tanh(acc + bias) * 127)
  #pragma unroll
  for (int ni = 0; ni < 4; ++ni) {
    int gn = bn * 256 + wn * 64 + ni * 16 + l15;
    float bv = bias[gn];
    #pragma unroll
    for (int mi = 0; mi < 4; ++mi) {
      int gmBase = bm * 256 + wm * 64 + mi * 16 + lg * 4;
      #pragma unroll
      for (int r = 0; r < 4; ++r) {
        float tv = tanhf(acc[mi][ni][r] + bv);
        feat[(size_t)(gmBase + r) * F2 + gn] = (int8_t)__float2int_rn(tv * 127.f);
      }
    }
  }
}

// ---------------- GEMM 2: 256x256 block, 16 waves (4x4), wave 64x64, 2-buf LDS, i8 ----------------
__global__ __launch_bounds__(1024, 4)
void k_expert_gemm256(const int8_t* __restrict__ A, const int8_t* __restrict__ Bt,
                      const float* __restrict__ P, const float* __restrict__ EB,
                      const float* __restrict__ SBq, float* __restrict__ out, int nbm) {
  constexpr int K = F2, NT = K / 64;          // 32 tiles of K=64
  __shared__ int8_t lds[2 * 16384 * 2];       // A: 2 x [256][64]B; B: 2 x [256][64]B
  int8_t* ldsB = lds + 32768;
  const int tid = threadIdx.x;
  const int l = tid & 63, wid = tid >> 6;
  const int wm = wid >> 2, wn = wid & 3;      // 4 x 4 waves, wave tile 64x64
  const int l15 = l & 15, lg = l >> 4;

  const int nwg = nbm * 16, cpx = nwg >> 3;   // NC/256 = 16 bn panels
  int swzb = (blockIdx.x & 7) * cpx + (blockIdx.x >> 3);
  const int bm = swzb % nbm, bn = swzb / nbm;

  const int8_t* gA = A  + (size_t)(bm * 256) * K;
  const int8_t* gB = Bt + (size_t)(bn * 256) * K;

  const int sRow = tid >> 2;
  const int sGx  = ((tid & 3) ^ ((sRow >> 1) & 3)) << 4;   // bytes

  #define STAGE(ts) do {                                                       \
    int b_ = (ts) & 1;                                                         \
    gload_lds16b(gA + (size_t)sRow * K + (ts) * 64 + sGx, lds  + b_ * 16384 + tid * 16); \
    gload_lds16b(gB + (size_t)sRow * K + (ts) * 64 + sGx, ldsB + b_ * 16384 + tid * 16); \
  } while (0)
  #define FENCE asm volatile("" ::: "memory")

  const int cswzB = ((lg ^ ((l15 >> 1) & 3)) << 4);
  i32x4 acc[4][4] = {};

  STAGE(0);
  asm volatile("s_waitcnt vmcnt(0)" ::: "memory");
  FENCE; __builtin_amdgcn_s_barrier(); FENCE;

  for (int t = 0; t < NT; ++t) {
    const int8_t* As_ = lds  + (t & 1) * 16384;
    const int8_t* Bs_ = ldsB + (t & 1) * 16384;
    if (t + 1 < NT) STAGE(t + 1);
    i32x4 af[4], bf[4];
    #pragma unroll
    for (int ni = 0; ni < 4; ++ni)
      bf[ni] = *(const i32x4*)&Bs_[(wn * 64 + ni * 16 + l15) * 64 + cswzB];
    #pragma unroll
    for (int mi = 0; mi < 4; ++mi)
      af[mi] = *(const i32x4*)&As_[(wm * 64 + mi * 16 + l15) * 64 + cswzB];
    __builtin_amdgcn_s_setprio(1);
    #pragma unroll
    for (int ni = 0; ni < 4; ++ni)
      #pragma unroll
      for (int mi = 0; mi < 4; ++mi)
        acc[mi][ni] = __builtin_amdgcn_mfma_i32_16x16x64_i8(af[mi], bf[ni], acc[mi][ni], 0, 0, 0);
    __builtin_amdgcn_s_setprio(0);
    asm volatile("s_waitcnt vmcnt(0)" ::: "memory");
    FENCE; __builtin_amdgcn_s_barrier(); FENCE;
  }
  #undef STAGE
  #undef FENCE

  // epilogue: dequant + gated combine -> fp32 out
  #pragma unroll
  for (int mi = 0; mi < 4; ++mi) {
    int gmBase = bm * 256 + wm * 64 + mi * 16 + lg * 4;
    float pr[4];
    #pragma unroll
    for (int r = 0; r < 4; ++r) pr[r] = P[(gmBase + r) * 4 + (l & 3)];
    #pragma unroll
    for (int ni = 0; ni < 4; ++ni) {
      int colp = bn * 256 + wn * 64 + ni * 16 + l15;
      int h = colp >> 2;
      float dq = SBq[colp] * (1.0f / 16129.0f);
      #pragma unroll
      for (int r = 0; r < 4; ++r) {
        float sv = (float)acc[mi][ni][r] * dq * pr[r];
        sv += __shfl_xor(sv, 1, 64);
        sv += __shfl_xor(sv, 2, 64);
        if ((l & 3) == 0) {
          int gm = gmBase + r;
          float bt = P[gm*4+0]*EB[h] + P[gm*4+1]*EB[Hh+h]
                   + P[gm*4+2]*EB[2*Hh+h] + P[gm*4+3]*EB[3*Hh+h];
          out[(size_t)gm * Hh + h] = sv + bt;
        }
      }
    }
  }
}

extern "C" void kernel_launch(void* const* d_in, const int* in_sizes, int n_in,
                              void* d_out, int out_size, void* d_ws, size_t ws_size,
                              hipStream_t stream) {
  const float *x  = (const float*)d_in[0],  *vol = (const float*)d_in[1];
  const float *risk = (const float*)d_in[2], *Wf = (const float*)d_in[3];
  const float *fb = (const float*)d_in[4],  *Wc = (const float*)d_in[5];
  const float *cb = (const float*)d_in[6],  *vw = (const float*)d_in[7];
  const float *vb = (const float*)d_in[8],  *rw = (const float*)d_in[9];
  const float *rb = (const float*)d_in[10], *sw = (const float*)d_in[11];
  const float *sb = (const float*)d_in[12], *We = (const float*)d_in[13];
  const float *eb = (const float*)d_in[14];

  float* out = (float*)d_out;   // fp32 output
  char* ws = (char*)d_ws;
  const size_t KB = 1024, MB = 1024 * 1024;

  float*  LP     = (float*) ws;                        // 256 KB
  float*  SBq    = (float*) (ws + 256 * KB);           // 16 KB
  float*  pmax   = (float*) (ws + 512 * KB);           // 128 KB
  bf16_t* wft    = (bf16_t*)(ws + 1 * MB);             // 4 MB
  int8_t* wet    = (int8_t*)(ws + 5 * MB);             // 8 MB
  bf16_t* xbf    = (bf16_t*)(ws + 13 * MB);            // 32 MB
  const size_t base = 45 * MB;
  int Tc = TOK;
  while (Tc > 1024 && base + (size_t)Tc * F2 > ws_size) Tc >>= 1;
  int8_t* feat = (int8_t*)(ws + base);                 // Tc * 2 KB

  k_tr_wf    <<<dim3(F2 / 64, Hh / 64), 256, 0, stream>>>(Wf, wft);
  k_we_scale1<<<dim3(4, 8, 4), 256, 0, stream>>>(We, pmax);
  k_we_scale2<<<16, 256, 0, stream>>>(pmax, SBq);
  k_tr_we    <<<dim3(F2 / 64, Hh / 64, 4), 256, 0, stream>>>(We, SBq, wet);

  for (int m0 = 0; m0 < TOK; m0 += Tc) {
    k_router_w<<<Tc / 4, 256, 0, stream>>>(
        x, vol, risk, cb, vw, vb, rw, rb, sw, sb, xbf, LP, m0, Tc);
    int nbmF = Tc / 256;
    k_feat_gemm256<<<nbmF * (F2 / 256), 1024, 0, stream>>>(
        xbf + (size_t)m0 * Hh, wft, fb, feat, nbmF);
    k_dom<<<Tc / 4, 256, 0, stream>>>(feat, Wc, LP);
    k_expert_gemm256<<<nbmF * (NC / 256), 1024, 0, stream>>>(
        feat, wet, LP, eb, SBq, out + (size_t)m0 * Hh, nbmF);
  }
}